// Round 11
// baseline (1511.034 us; speedup 1.0000x reference)
//
#include <hip/hip_runtime.h>
#include <math.h>

// Glacier SIA stepper. 256 persistent blocks x 512 threads, HR=2 (2 owned
// rows/block) -> ALL 256 CUs active, ~0.6x per-CU work vs the 128-block R10.
// R10 protocol verbatim: epoch-tagged halo words {epoch<<32|float} posted
// EARLY via relaxed 8B agent-scope atomics; depth-2 parity buffers; direct
// 256-wide ring gather; pre-barrier ring post. Strength-reduced arithmetic
// (folded /200 scalings, sqrt^2 identity).
// HR=2 geometry: both neighbors consume the SAME central D row (row a), so
// one cD array replaces upD/dnD.
//
// Register-slot maps (block first owned row a = 2*w):
//   zs[s]  = Zs row a-2+s   (s=0..5; 0,5 halo)
//   Dv[ld] = D  row a-2+ld  (ld=0..4; 0,4 halo)
//   h/hn/smbr/dH[ln] = row a-1+ln (ln=0..3); mid ln=1,2; edges ln=0,3
// Posts: dnH=hn row a (ln=1), upH=hn row a+1 (ln=2), cD=D row a (ph2 ln=1).
// Reads: top zs halo row a-2 = dnH[w-1]; bottom row a+3 = upH[w+1];
//        top D halo row a-2 = cD[w-1]; bottom row a+2 = cD[w+1].
//
// ws layout (bytes):
//   0      : ull ring[2][256] lines (stride 128 B) {epoch<<32 | blockMax}
//   65536  : ull upH[2][256][512], dnH[...], cD[...]  (6 MB tagged halos)

#define NN 512
#define MM (NN * NN)
#define NSTEPS 400
#define NW 256
#define HR 2
#define TPB 512

typedef unsigned long long ull;

__device__ __forceinline__ ull ald(const ull* p) {
  return __hip_atomic_load(p, __ATOMIC_RELAXED, __HIP_MEMORY_SCOPE_AGENT);
}
__device__ __forceinline__ void asto(ull* p, ull v) {
  __hip_atomic_store(p, v, __ATOMIC_RELAXED, __HIP_MEMORY_SCOPE_AGENT);
}

__global__ __launch_bounds__(TPB)
void glacier_kernel(const float* __restrict__ Zt,
                    const float* __restrict__ precip,
                    const float* __restrict__ Tm,
                    const float* __restrict__ Ts,
                    float* __restrict__ out,        // [3*MM]: H1, H2, H
                    ull* __restrict__ ring,         // [2][256] lines
                    ull* __restrict__ halo) {       // upH, dnH, cD
  __shared__ float Zs2[2][HR + 4][NN];
  __shared__ float DB[HR + 3][NN];
  __shared__ float HnB[HR + 2][NN];
  __shared__ float gmax4[4];
  __shared__ unsigned lmx[2], lcnt[2];

  ull* upH = halo;                    // [2][NW][NN] each
  ull* dnH = halo + 2 * NW * NN;
  ull* cD  = halo + 4 * NW * NN;

  const int w = blockIdx.x;
  const int j = threadIdx.x;          // column
  const int lane = j & 63;
  const int a = w * HR;               // first owned row
  const bool hasT = (w > 0), hasB = (w < NW - 1);
  const float TmTs = Tm[0] + Ts[0];
  const double RG = 910.0 * 9.81;
  const float CDIF = (float)(1e-16 * RG * RG * RG);
  const float C_Q = 1.25e-5f;         // folded flux scaling
  const float C_S2 = 6.25e-6f;        // (0.5/200)^2 slope scaling
  const size_t wofs = (size_t)w * NN;

  float ztreg[HR + 4];
  float hcur[HR + 2];
  float smbreg[HR + 2];

  // ---- prologue (no cross-block deps)
#pragma unroll
  for (int ls = 0; ls < HR + 4; ++ls) {
    int r = a - 2 + ls;
    float zt = (r >= 0 && r < NN) ? Zt[r * NN + j] : 0.f;
    ztreg[ls] = zt;
    Zs2[0][ls][j] = zt;               // H = 0
  }
#pragma unroll
  for (int ln = 0; ln < HR + 2; ++ln) {
    int r = a - 1 + ln;
    hcur[ln] = 0.f;
    float sm = 0.f;
    if (r >= 0 && r < NN) {
      float T = TmTs - 0.006f * ztreg[ln + 1];
      sm = precip[r * NN + j] - 0.5f * fmaxf(T, 0.f);
    }
    smbreg[ln] = sm;
  }
#pragma unroll
  for (int ld = 0; ld < HR + 3; ++ld) DB[ld][j] = 1e-10f;    // D(H=0) exactly
#pragma unroll
  for (int rr = 0; rr < HR; ++rr) {
    int id = (a + rr) * NN + j;
    out[id] = 0.f;
    out[MM + id] = 0.f;
  }
  if (j == 0) { lmx[0] = 0u; lmx[1] = 0u; lcnt[0] = 0u; lcnt[1] = 0u; }
  __syncthreads();                    // prologue LDS visible

  float time = 0.f, t_last = 0.f;
  int idx = 0;
  bool s1 = false, s2 = false;

  for (int k = 0; k < NSTEPS; ++k) {
    if (time >= 200.0f) break;                  // uniform (dt identical)

    const int p = k & 1;
    const size_t pc = (size_t)(k & 1) * NW * NN;        // consume parity
    const size_t pn = (size_t)((k + 1) & 1) * NW * NN;  // produce parity
    const ull tg = ((ull)(unsigned)(k + 1)) << 32;      // produce tag
    ull* ringp = ring + (size_t)(k & 1) * NW * 16;

    // reset the LDS max/cnt slot step k+1 will use (safe: sync3(k-1) passed)
    if (j == 0) { lmx[(k + 1) & 1] = 0u; lcnt[(k + 1) & 1] = 0u; }

    // ---- top samples (issue early; checked after mid compute)
    bool pre = (time - t_last) >= 4.0f;         // exact-safe precip gate
    int idxn = min(idx + 1, 63);
    float pf[HR + 2];
    if (pre) {
      const float* prowN = precip + (size_t)idxn * MM;
#pragma unroll
      for (int ln = 0; ln < HR + 2; ++ln) {
        int i = a - 1 + ln;
        pf[ln] = (i >= 0 && i < NN) ? prowN[i * NN + j] : 0.f;
      }
    } else {
#pragma unroll
      for (int ln = 0; ln < HR + 2; ++ln) pf[ln] = 0.f;
    }
    const ull *pHt = nullptr, *pDt = nullptr, *pHb = nullptr, *pDb = nullptr;
    ull vHt = 0, vDt = 0, vHb = 0, vDb = 0;
    const ull* gp = nullptr; ull gv = 0;
    if (k > 0) {
      if (hasT) {
        pHt = dnH + pc + (size_t)(w - 1) * NN + j;
        pDt = cD  + pc + (size_t)(w - 1) * NN + j;
        vHt = ald(pHt);
        if (j < NN - 1) vDt = ald(pDt);
      }
      if (hasB) {
        pHb = upH + pc + (size_t)(w + 1) * NN + j;
        pDb = cD  + pc + (size_t)(w + 1) * NN + j;
        vHb = ald(pHb);
        if (j < NN - 1) vDb = ald(pDb);
      }
      if (j < NW) { gp = ringp + j * 16; gv = ald(gp); }   // gather sample
    }
    asm volatile("" ::: "memory");

    // ---- part A mid: dHdt rows a..a+1 (halo-free; hides sample RTs)
    float dHdt[HR + 2];
#pragma unroll
    for (int ln = 1; ln <= HR; ++ln) {
      int i = a - 1 + ln;
      float v = 0.f;
      if (i > 0 && i < NN - 1 && j > 0 && j < NN - 1) {
        int li = ln + 1;
        float zc = Zs2[p][li][j];
        float zw = Zs2[p][li][j - 1];
        float ze = Zs2[p][li][j + 1];
        float zn = Zs2[p][li - 1][j];
        float zs_ = Zs2[p][li + 1][j];
        float d00 = DB[ln][j - 1], d01 = DB[ln][j];
        float d10 = DB[ln + 1][j - 1], d11 = DB[ln + 1][j];
        v = C_Q * (((d01 + d11) * (ze - zc) - (d00 + d10) * (zc - zw)) +
                   ((d10 + d11) * (zs_ - zc) - (d00 + d01) * (zc - zn)));
      }
      dHdt[ln] = v;
    }

    // ---- halo tag checks (data+readiness in one word) + gather spin
    if (k > 0) {
      if (pHt) {
        while ((unsigned)(vHt >> 32) < (unsigned)k) {
          __builtin_amdgcn_s_sleep(1); vHt = ald(pHt);
        }
        if (j < NN - 1)
          while ((unsigned)(vDt >> 32) < (unsigned)k) {
            __builtin_amdgcn_s_sleep(1); vDt = ald(pDt);
          }
      }
      if (pHb) {
        while ((unsigned)(vHb >> 32) < (unsigned)k) {
          __builtin_amdgcn_s_sleep(1); vHb = ald(pHb);
        }
        if (j < NN - 1)
          while ((unsigned)(vDb >> 32) < (unsigned)k) {
            __builtin_amdgcn_s_sleep(1); vDb = ald(pDb);
          }
      }
      if (j < NW) {                             // direct gather (waves 0..3)
        while ((unsigned)(gv >> 32) < (unsigned)k) {
          __builtin_amdgcn_s_sleep(1); gv = ald(gp);
        }
        float lm = __uint_as_float((unsigned)gv);
        for (int off = 32; off; off >>= 1) lm = fmaxf(lm, __shfl_xor(lm, off));
        if (lane == 0) gmax4[j >> 6] = lm;
      }
      // stage halos into LDS
      if (pHt) {
        Zs2[p][0][j] = ztreg[0] + __uint_as_float((unsigned)vHt);
        if (j < NN - 1) DB[0][j] = __uint_as_float((unsigned)vDt);
      }
      if (pHb) {
        Zs2[p][HR + 3][j] = ztreg[HR + 3] + __uint_as_float((unsigned)vHb);
        if (j < NN - 1) DB[HR + 2][j] = __uint_as_float((unsigned)vDb);
      }
    }
    __syncthreads();                            // sync1: halos + gmax4 visible

    // ---- part A edges: dHdt rows a-1, a+2
#pragma unroll
    for (int ln = 0; ln <= HR + 1; ln += HR + 1) {
      int i = a - 1 + ln;
      float v = 0.f;
      if (i > 0 && i < NN - 1 && j > 0 && j < NN - 1) {
        int li = ln + 1;
        float zc = Zs2[p][li][j];
        float zw = Zs2[p][li][j - 1];
        float ze = Zs2[p][li][j + 1];
        float zn = Zs2[p][li - 1][j];
        float zs_ = Zs2[p][li + 1][j];
        float d00 = DB[ln][j - 1], d01 = DB[ln][j];
        float d10 = DB[ln + 1][j - 1], d11 = DB[ln + 1][j];
        v = C_Q * (((d01 + d11) * (ze - zc) - (d00 + d10) * (zc - zw)) +
                   ((d10 + d11) * (zs_ - zc) - (d00 + d01) * (zc - zn)));
      }
      dHdt[ln] = v;
    }

    float maxD = (k == 0) ? 1e-10f
               : fmaxf(fmaxf(gmax4[0], gmax4[1]), fmaxf(gmax4[2], gmax4[3]));
    float dt = fminf(40000.0f / (2.7f * maxD), 1.0f);
    float tnew = time + dt;
    bool cap1 = (!s1) && (tnew >= 120.0f);
    bool cap2 = (!s2) && (tnew >= 160.0f);
    bool do_upd = (tnew - t_last) >= 5.0f;

    // ---- part B: H update, EARLY tagged H-halo posts, captures, smb
    float hnxt[HR + 2];
#pragma unroll
    for (int ln = 0; ln < HR + 2; ++ln) {
      int i = a - 1 + ln;
      float hnew = 0.f;
      if (i >= 0 && i < NN) {
        if (i > 0 && i < NN - 1 && j > 0 && j < NN - 1)
          hnew = fmaxf(hcur[ln] + dt * (dHdt[ln] + smbreg[ln]), 0.f);
        float zsn = ztreg[ln + 1] + hnew;
        HnB[ln][j] = hnew;
        Zs2[p ^ 1][ln + 1][j] = zsn;
        if (ln == 1) asto(dnH + pn + wofs + j, tg | (ull)__float_as_uint(hnew));
        if (ln == 2) asto(upH + pn + wofs + j, tg | (ull)__float_as_uint(hnew));
        if (i >= a && i < a + HR) {
          int id = i * NN + j;
          if (cap1) out[id] = hnew;
          if (cap2) out[MM + id] = hnew;
        }
        if (do_upd)
          smbreg[ln] = pf[ln] - 0.5f * fmaxf(TmTs - 0.006f * zsn, 0.f);
      }
      hnxt[ln] = hnew;
    }
    __syncthreads();                            // sync2: HnB/Zs2^1 visible

    // ---- phase 2: new D rows a-1..a+1 + EARLY tagged D-halo post + max
    float lmax = 0.f;
#pragma unroll
    for (int ln = 0; ln < HR + 1; ++ln) {
      int r = a - 1 + ln;
      if (r >= 0 && r < NN - 1 && j < NN - 1) {
        float h00 = HnB[ln][j], h01 = HnB[ln][j + 1];
        float h10 = HnB[ln + 1][j], h11 = HnB[ln + 1][j + 1];
        float z00 = Zs2[p ^ 1][ln + 1][j], z01 = Zs2[p ^ 1][ln + 1][j + 1];
        float z10 = Zs2[p ^ 1][ln + 2][j], z11 = Zs2[p ^ 1][ln + 2][j + 1];
        float havg = 0.25f * (((h00 + h11) + h01) + h10);
        float u = (z01 - z00) + (z11 - z10);
        float vv = (z10 - z00) + (z11 - z01);
        float s2 = C_S2 * (u * u + vv * vv) + 1e-10f;   // == Snorm^2
        float h2 = havg * havg;
        float h4 = h2 * h2;
        float h5 = h4 * havg;
        float d = CDIF * h5 * s2 + 1e-10f;
        DB[ln + 1][j] = d;
        if (ln == 1) asto(cD + pn + wofs + j, tg | (ull)__float_as_uint(d));
        lmax = fmaxf(lmax, d);
      }
    }
    for (int off = 32; off; off >>= 1) lmax = fmaxf(lmax, __shfl_xor(lmax, off));
    // pre-barrier ring post: last-arriving wave publishes the block max
    if (lane == 0) {
      atomicMax(&lmx[k & 1], __float_as_uint(lmax));   // D>0: uint-monotone
      unsigned c = atomicAdd(&lcnt[k & 1], 1u);
      if (c == 7u) {
        unsigned mv = atomicAdd(&lmx[k & 1], 0u);      // atomic read-back
        asto(ring + (size_t)((k + 1) & 1) * NW * 16 + w * 16,
             ((ull)(unsigned)(k + 1) << 32) | (ull)mv);
      }
    }

    // ---- bookkeeping + step-close barrier (protects LDS reuse next step)
#pragma unroll
    for (int ln = 0; ln < HR + 2; ++ln) hcur[ln] = hnxt[ln];
    time = tnew;
    s1 = s1 || cap1;
    s2 = s2 || cap2;
    if (do_upd) { idx = idxn; t_last = tnew; }
    __syncthreads();                            // sync3
  }

  // ---- final H (owned rows; hcur slot for row a+rr is rr+1)
#pragma unroll
  for (int rr = 0; rr < HR; ++rr)
    out[2 * MM + (a + rr) * NN + j] = hcur[rr + 1];
}

extern "C" void kernel_launch(void* const* d_in, const int* in_sizes, int n_in,
                              void* d_out, int out_size, void* d_ws, size_t ws_size,
                              hipStream_t stream) {
  const float* Zt = (const float*)d_in[0];
  const float* precip = (const float*)d_in[1];
  const float* Tm = (const float*)d_in[2];
  const float* Ts = (const float*)d_in[3];
  float* out = (float*)d_out;

  ull* ring = (ull*)d_ws;                            // 2*256 lines @ 128 B
  ull* halo = (ull*)((char*)d_ws + 65536);           // 6 MB tagged halos

  // zero ring tags + halo tags (ws is not re-poisoned between replays)
  hipMemsetAsync(d_ws, 0, 65536 + (size_t)6 * NW * NN * sizeof(ull), stream);
  glacier_kernel<<<NW, TPB, 0, stream>>>(Zt, precip, Tm, Ts, out, ring, halo);
}

// Round 12
// 1270.350 us; speedup vs baseline: 1.1895x; 1.1895x over previous
//
#include <hip/hip_runtime.h>
#include <math.h>

// Glacier SIA stepper. 128 persistent blocks x 512 threads (R10 geometry).
// R12: global-gather decoupled from barriers. sync1 orders only neighbor
// halo staging; waves 0,1 gather the 128 ring slots AFTER sync1 (overlapping
// the other 6 waves' edge-row compute) and publish {epoch<<32|max} as a
// tagged LDS word; consumers spin on it (LDS RT, no barrier) right before
// the dt-dependent H-update. sd = dHdt+smb precomputed so part B is 1 fma.
// Epoch-tagged halo words + depth-2 parity + pre-barrier ring post as R10.
//
// ws layout (bytes):
//   0      : ull ring[2][128] lines (stride 128 B) {epoch<<32 | blockMax}
//   32768  : ull halo[4][2][NW][NN]  (upH, upD, dnH, dnD; 4 MB)

#define NN 512
#define MM (NN * NN)
#define NSTEPS 400
#define NW 128
#define HR 4
#define TPB 512

typedef unsigned long long ull;

__device__ __forceinline__ ull ald(const ull* p) {
  return __hip_atomic_load(p, __ATOMIC_RELAXED, __HIP_MEMORY_SCOPE_AGENT);
}
__device__ __forceinline__ void asto(ull* p, ull v) {
  __hip_atomic_store(p, v, __ATOMIC_RELAXED, __HIP_MEMORY_SCOPE_AGENT);
}
__device__ __forceinline__ ull lld(const ull* p) {
  return __hip_atomic_load(p, __ATOMIC_RELAXED, __HIP_MEMORY_SCOPE_WORKGROUP);
}
__device__ __forceinline__ void lst(ull* p, ull v) {
  __hip_atomic_store(p, v, __ATOMIC_RELAXED, __HIP_MEMORY_SCOPE_WORKGROUP);
}

__global__ __launch_bounds__(TPB)
void glacier_kernel(const float* __restrict__ Zt,
                    const float* __restrict__ precip,
                    const float* __restrict__ Tm,
                    const float* __restrict__ Ts,
                    float* __restrict__ out,        // [3*MM]: H1, H2, H
                    ull* __restrict__ ring,         // [2][128] lines
                    ull* __restrict__ halo) {       // [4][2][NW][NN]
  __shared__ float Zs2[2][HR + 4][NN];
  __shared__ float DB[HR + 3][NN];
  __shared__ float HnB[HR + 2][NN];
  __shared__ ull gm[2];               // tagged {epoch<<32 | partial-max bits}
  __shared__ unsigned lmx[2], lcnt[2];

  ull* upH = halo;                    // [2][NW][NN] each
  ull* upD = halo + 2 * NW * NN;
  ull* dnH = halo + 4 * NW * NN;
  ull* dnD = halo + 6 * NW * NN;

  const int w = blockIdx.x;
  const int j = threadIdx.x;          // column
  const int lane = j & 63;
  const int a = w * HR;               // first owned row
  const bool hasT = (w > 0), hasB = (w < NW - 1);
  const float TmTs = Tm[0] + Ts[0];
  const double RG = 910.0 * 9.81;
  const float CDIF = (float)(1e-16 * RG * RG * RG);
  const float C_Q = 1.25e-5f;         // folded flux scaling
  const float C_S2 = 6.25e-6f;        // (0.5/200)^2 slope scaling
  const size_t wofs = (size_t)w * NN;

  float ztreg[HR + 4];
  float hcur[HR + 2];
  float smbreg[HR + 2];

  // ---- prologue (no cross-block deps)
#pragma unroll
  for (int ls = 0; ls < HR + 4; ++ls) {
    int r = a - 2 + ls;
    float zt = (r >= 0 && r < NN) ? Zt[r * NN + j] : 0.f;
    ztreg[ls] = zt;
    Zs2[0][ls][j] = zt;               // H = 0
  }
#pragma unroll
  for (int ln = 0; ln < HR + 2; ++ln) {
    int r = a - 1 + ln;
    hcur[ln] = 0.f;
    float sm = 0.f;
    if (r >= 0 && r < NN) {
      float T = TmTs - 0.006f * ztreg[ln + 1];
      sm = precip[r * NN + j] - 0.5f * fmaxf(T, 0.f);
    }
    smbreg[ln] = sm;
  }
#pragma unroll
  for (int ld = 0; ld < HR + 3; ++ld) DB[ld][j] = 1e-10f;    // D(H=0) exactly
#pragma unroll
  for (int rr = 0; rr < HR; ++rr) {
    int id = (a + rr) * NN + j;
    out[id] = 0.f;
    out[MM + id] = 0.f;
  }
  if (j == 0) { lmx[0] = 0u; lmx[1] = 0u; lcnt[0] = 0u; lcnt[1] = 0u;
                gm[0] = 0ull; gm[1] = 0ull; }
  __syncthreads();                    // prologue LDS visible

  float time = 0.f, t_last = 0.f;
  int idx = 0;
  bool s1 = false, s2 = false;

  for (int k = 0; k < NSTEPS; ++k) {
    if (time >= 200.0f) break;                  // uniform (dt identical)

    const int p = k & 1;
    const size_t pc = (size_t)(k & 1) * NW * NN;        // consume parity
    const size_t pn = (size_t)((k + 1) & 1) * NW * NN;  // produce parity
    const ull tg = ((ull)(unsigned)(k + 1)) << 32;      // produce tag
    ull* ringp = ring + (size_t)(k & 1) * NW * 16;

    // reset the LDS max/cnt slot step k+1 will use (safe: sync3(k-1) passed)
    if (j == 0) { lmx[(k + 1) & 1] = 0u; lcnt[(k + 1) & 1] = 0u; }

    // ---- top samples (issue early; checked after mid compute)
    bool pre = (time - t_last) >= 4.0f;         // exact-safe precip gate
    int idxn = min(idx + 1, 63);
    float pf[HR + 2];
    if (pre) {
      const float* prowN = precip + (size_t)idxn * MM;
#pragma unroll
      for (int ln = 0; ln < HR + 2; ++ln) {
        int i = a - 1 + ln;
        pf[ln] = (i >= 0 && i < NN) ? prowN[i * NN + j] : 0.f;
      }
    } else {
#pragma unroll
      for (int ln = 0; ln < HR + 2; ++ln) pf[ln] = 0.f;
    }
    const ull *pHt = nullptr, *pDt = nullptr, *pHb = nullptr, *pDb = nullptr;
    ull vHt = 0, vDt = 0, vHb = 0, vDb = 0;
    const ull* gp = nullptr; ull gv = 0;
    if (k > 0) {
      if (hasT) {
        pHt = dnH + pc + (size_t)(w - 1) * NN + j;
        pDt = dnD + pc + (size_t)(w - 1) * NN + j;
        vHt = ald(pHt);
        if (j < NN - 1) vDt = ald(pDt);
      }
      if (hasB) {
        pHb = upH + pc + (size_t)(w + 1) * NN + j;
        pDb = upD + pc + (size_t)(w + 1) * NN + j;
        vHb = ald(pHb);
        if (j < NN - 1) vDb = ald(pDb);
      }
      if (j < NW) { gp = ringp + j * 16; gv = ald(gp); }   // gather sample
    }
    asm volatile("" ::: "memory");

    // ---- part A mid: dHdt rows a..a+3 (halo-free; hides sample RTs)
    float dHdt[HR + 2];
#pragma unroll
    for (int ln = 1; ln <= HR; ++ln) {
      int i = a - 1 + ln;
      float v = 0.f;
      if (i > 0 && i < NN - 1 && j > 0 && j < NN - 1) {
        int li = ln + 1;
        float zc = Zs2[p][li][j];
        float zw = Zs2[p][li][j - 1];
        float ze = Zs2[p][li][j + 1];
        float zn = Zs2[p][li - 1][j];
        float zs_ = Zs2[p][li + 1][j];
        float d00 = DB[ln][j - 1], d01 = DB[ln][j];
        float d10 = DB[ln + 1][j - 1], d11 = DB[ln + 1][j];
        v = C_Q * (((d01 + d11) * (ze - zc) - (d00 + d10) * (zc - zw)) +
                   ((d10 + d11) * (zs_ - zc) - (d00 + d01) * (zc - zn)));
      }
      dHdt[ln] = v;
    }

    // ---- neighbor halo tag checks + staging (NO gather here)
    if (k > 0) {
      if (pHt) {
        while ((unsigned)(vHt >> 32) < (unsigned)k) {
          __builtin_amdgcn_s_sleep(1); vHt = ald(pHt);
        }
        if (j < NN - 1)
          while ((unsigned)(vDt >> 32) < (unsigned)k) {
            __builtin_amdgcn_s_sleep(1); vDt = ald(pDt);
          }
      }
      if (pHb) {
        while ((unsigned)(vHb >> 32) < (unsigned)k) {
          __builtin_amdgcn_s_sleep(1); vHb = ald(pHb);
        }
        if (j < NN - 1)
          while ((unsigned)(vDb >> 32) < (unsigned)k) {
            __builtin_amdgcn_s_sleep(1); vDb = ald(pDb);
          }
      }
      // stage halos into LDS
      if (pHt) {
        Zs2[p][0][j] = ztreg[0] + __uint_as_float((unsigned)vHt);
        if (j < NN - 1) DB[0][j] = __uint_as_float((unsigned)vDt);
      }
      if (pHb) {
        Zs2[p][HR + 3][j] = ztreg[HR + 3] + __uint_as_float((unsigned)vHb);
        if (j < NN - 1) DB[HR + 2][j] = __uint_as_float((unsigned)vDb);
      }
    }
    __syncthreads();                  // sync1: neighbor halos visible (local!)

    // ---- gather waves (0,1): spin on ring, publish tagged LDS word.
    //      Overlaps the other 6 waves' edge-row compute below.
    if (k > 0 && j < NW) {
      while ((unsigned)(gv >> 32) < (unsigned)k) {
        __builtin_amdgcn_s_sleep(1); gv = ald(gp);
      }
      float lm = __uint_as_float((unsigned)gv);
      for (int off = 32; off; off >>= 1) lm = fmaxf(lm, __shfl_xor(lm, off));
      if (lane == 0)
        lst(&gm[j >> 6], ((ull)(unsigned)k << 32) | (ull)__float_as_uint(lm));
    }

    // ---- part A edges: dHdt rows a-1, a+4 (uses staged halos)
#pragma unroll
    for (int ln = 0; ln <= HR + 1; ln += HR + 1) {
      int i = a - 1 + ln;
      float v = 0.f;
      if (i > 0 && i < NN - 1 && j > 0 && j < NN - 1) {
        int li = ln + 1;
        float zc = Zs2[p][li][j];
        float zw = Zs2[p][li][j - 1];
        float ze = Zs2[p][li][j + 1];
        float zn = Zs2[p][li - 1][j];
        float zs_ = Zs2[p][li + 1][j];
        float d00 = DB[ln][j - 1], d01 = DB[ln][j];
        float d10 = DB[ln + 1][j - 1], d11 = DB[ln + 1][j];
        v = C_Q * (((d01 + d11) * (ze - zc) - (d00 + d10) * (zc - zw)) +
                   ((d10 + d11) * (zs_ - zc) - (d00 + d01) * (zc - zn)));
      }
      dHdt[ln] = v;
    }

    // ---- dt-independent sum (so part B is a single fma per row)
    float sd[HR + 2];
#pragma unroll
    for (int ln = 0; ln < HR + 2; ++ln) sd[ln] = dHdt[ln] + smbreg[ln];

    // ---- dt: spin on the tagged LDS gather words (cheap, no barrier)
    float maxD;
    if (k == 0) {
      maxD = 1e-10f;
    } else {
      ull g0 = lld(&gm[0]);
      while ((unsigned)(g0 >> 32) < (unsigned)k) {
        __builtin_amdgcn_s_sleep(1); g0 = lld(&gm[0]);
      }
      ull g1 = lld(&gm[1]);
      while ((unsigned)(g1 >> 32) < (unsigned)k) {
        __builtin_amdgcn_s_sleep(1); g1 = lld(&gm[1]);
      }
      maxD = fmaxf(__uint_as_float((unsigned)g0),
                   __uint_as_float((unsigned)g1));
    }
    float dt = fminf(40000.0f / (2.7f * maxD), 1.0f);
    float tnew = time + dt;
    bool cap1 = (!s1) && (tnew >= 120.0f);
    bool cap2 = (!s2) && (tnew >= 160.0f);
    bool do_upd = (tnew - t_last) >= 5.0f;

    // ---- part B: H update, EARLY tagged H-halo posts, captures, smb
    float hnxt[HR + 2];
#pragma unroll
    for (int ln = 0; ln < HR + 2; ++ln) {
      int i = a - 1 + ln;
      float hnew = 0.f;
      if (i >= 0 && i < NN) {
        if (i > 0 && i < NN - 1 && j > 0 && j < NN - 1)
          hnew = fmaxf(fmaf(dt, sd[ln], hcur[ln]), 0.f);
        float zsn = ztreg[ln + 1] + hnew;
        HnB[ln][j] = hnew;
        Zs2[p ^ 1][ln + 1][j] = zsn;
        if (ln == 2) asto(upH + pn + wofs + j, tg | (ull)__float_as_uint(hnew));
        if (ln == 3) asto(dnH + pn + wofs + j, tg | (ull)__float_as_uint(hnew));
        if (i >= a && i < a + HR) {
          int id = i * NN + j;
          if (cap1) out[id] = hnew;
          if (cap2) out[MM + id] = hnew;
        }
        if (do_upd)
          smbreg[ln] = pf[ln] - 0.5f * fmaxf(TmTs - 0.006f * zsn, 0.f);
      }
      hnxt[ln] = hnew;
    }
    __syncthreads();                            // sync2: HnB/Zs2^1 visible

    // ---- phase 2: new D rows a-1..a+3 + EARLY tagged D-halo posts + max
    float lmax = 0.f;
#pragma unroll
    for (int ln = 0; ln < HR + 1; ++ln) {
      int r = a - 1 + ln;
      if (r >= 0 && r < NN - 1 && j < NN - 1) {
        float h00 = HnB[ln][j], h01 = HnB[ln][j + 1];
        float h10 = HnB[ln + 1][j], h11 = HnB[ln + 1][j + 1];
        float z00 = Zs2[p ^ 1][ln + 1][j], z01 = Zs2[p ^ 1][ln + 1][j + 1];
        float z10 = Zs2[p ^ 1][ln + 2][j], z11 = Zs2[p ^ 1][ln + 2][j + 1];
        float havg = 0.25f * (((h00 + h11) + h01) + h10);
        float u = (z01 - z00) + (z11 - z10);
        float vv = (z10 - z00) + (z11 - z01);
        float s2 = C_S2 * (u * u + vv * vv) + 1e-10f;   // == Snorm^2
        float h2 = havg * havg;
        float h4 = h2 * h2;
        float h5 = h4 * havg;
        float d = CDIF * h5 * s2 + 1e-10f;
        DB[ln + 1][j] = d;
        if (ln == 1) asto(upD + pn + wofs + j, tg | (ull)__float_as_uint(d));
        if (ln == 3) asto(dnD + pn + wofs + j, tg | (ull)__float_as_uint(d));
        lmax = fmaxf(lmax, d);
      }
    }
    for (int off = 32; off; off >>= 1) lmax = fmaxf(lmax, __shfl_xor(lmax, off));
    // pre-barrier ring post: last-arriving wave publishes the block max
    if (lane == 0) {
      atomicMax(&lmx[k & 1], __float_as_uint(lmax));   // D>0: uint-monotone
      unsigned c = atomicAdd(&lcnt[k & 1], 1u);
      if (c == 7u) {
        unsigned mv = atomicAdd(&lmx[k & 1], 0u);      // atomic read-back
        asto(ring + (size_t)((k + 1) & 1) * NW * 16 + w * 16,
             ((ull)(unsigned)(k + 1) << 32) | (ull)mv);
      }
    }

    // ---- bookkeeping + step-close barrier (protects LDS reuse next step)
#pragma unroll
    for (int ln = 0; ln < HR + 2; ++ln) hcur[ln] = hnxt[ln];
    time = tnew;
    s1 = s1 || cap1;
    s2 = s2 || cap2;
    if (do_upd) { idx = idxn; t_last = tnew; }
    __syncthreads();                            // sync3
  }

  // ---- final H (owned rows; hcur slot for row a+rr is rr+1)
#pragma unroll
  for (int rr = 0; rr < HR; ++rr)
    out[2 * MM + (a + rr) * NN + j] = hcur[rr + 1];
}

extern "C" void kernel_launch(void* const* d_in, const int* in_sizes, int n_in,
                              void* d_out, int out_size, void* d_ws, size_t ws_size,
                              hipStream_t stream) {
  const float* Zt = (const float*)d_in[0];
  const float* precip = (const float*)d_in[1];
  const float* Tm = (const float*)d_in[2];
  const float* Ts = (const float*)d_in[3];
  float* out = (float*)d_out;

  ull* ring = (ull*)d_ws;                            // 2*128 lines @ 128 B
  ull* halo = (ull*)((char*)d_ws + 32768);           // 4 MB tagged halos

  // zero ring tags + halo tags (ws is not re-poisoned between replays)
  hipMemsetAsync(d_ws, 0, 32768 + (size_t)8 * NW * NN * sizeof(ull), stream);
  glacier_kernel<<<NW, TPB, 0, stream>>>(Zt, precip, Tm, Ts, out, ring, halo);
}